// Round 12
// baseline (90.991 us; speedup 1.0000x reference)
//
#include <hip/hip_runtime.h>
#include <hip/hip_bf16.h>
#include <math.h>

// Problem shape (fixed by setup_inputs): B=128, S=20, C=32000
#define NB 128
#define NS 20
#define NC 32000
#define NROWS (NB * NS)            // 2560
#define NBLOCKS (NB + NROWS)       // 2688 singleton-wave blocks (~10.5/CU)

// min with lane^1 / lane^2 via DPP quad_perm (pure VALU, no LDS)
static __device__ __forceinline__ float fmin_x1(float x) {
    int t = __builtin_amdgcn_update_dpp(0, __float_as_int(x), 0xB1, 0xf, 0xf, true); // [1,0,3,2]
    return fminf(x, __int_as_float(t));
}
static __device__ __forceinline__ float fmin_x2(float x) {
    int t = __builtin_amdgcn_update_dpp(0, __float_as_int(x), 0x4E, 0xf, 0xf, true); // [2,3,0,1]
    return fminf(x, __int_as_float(t));
}
// min with lane^4 / ^8 / ^16 via ds_swizzle bitmode (1 LDS-pipe op each)
static __device__ __forceinline__ float fmin_x4(float x) {
    int t = __builtin_amdgcn_ds_swizzle(__float_as_int(x), 0x101F);
    return fminf(x, __int_as_float(t));
}
static __device__ __forceinline__ float fmin_x8(float x) {
    int t = __builtin_amdgcn_ds_swizzle(__float_as_int(x), 0x201F);
    return fminf(x, __int_as_float(t));
}
static __device__ __forceinline__ float fmin_x16(float x) {
    int t = __builtin_amdgcn_ds_swizzle(__float_as_int(x), 0x401F);
    return fminf(x, __int_as_float(t));
}
static __device__ __forceinline__ float readlane_f(float x, int lane) {
    return __int_as_float(__builtin_amdgcn_readlane(__float_as_int(x), lane));
}
static __device__ __forceinline__ float max4(float4 a) {
    return fmaxf(fmaxf(a.x, a.y), fmaxf(a.z, a.w));
}

// ---------------------------------------------------------------------------
// Mega kernel, 64-thread (single-wave) blocks, ZERO cross-block sync and now
// ZERO intra-block convoying on the stream path:
//   bid <  NB : fused gather + restricted-softmax cost + wave-parallel
//               Hungarian for batch bid (one wave does everything).
//   bid >= NB : ONE LSE row per wave: 125 float4/lane, 8-deep independent
//               loads, wave-only shuffle reduce, no LDS, no barriers.
// ---------------------------------------------------------------------------
__global__ __launch_bounds__(64) void mega_kernel(
        const float* __restrict__ outputs,
        const int* __restrict__ gold,
        const float* __restrict__ weight,
        int* __restrict__ match_col,     // [NROWS] assigned 0-based column per row
        float* __restrict__ sub_ws,      // [NROWS*NS] raw gathered logits
        float* __restrict__ logZ) {      // [NROWS]

    const int bid = blockIdx.x;
    const int lane = threadIdx.x;        // 0..63

    if (bid < NB) {
        // =================== fused cost + wave Hungarian ===================
        const int b = bid;
        const int* g = gold + b * NS;
        __shared__ float cst[NS * NS];   // sub logits, then cost, in place
        __shared__ float lzs[NS];

        // phase 1: gather outputs[b, i, gold[b, j]] + save raw logits to ws
        for (int e = lane; e < NS * NS; e += 64) {
            int i = e / NS, j = e - i * NS;
            float x = outputs[(size_t)(b * NS + i) * NC + g[j]];
            cst[e] = x;
            sub_ws[(size_t)(b * NS + i) * NS + j] = x;
        }
        __syncthreads();
        // phase 2: per-row restricted logsumexp over the 20 gold columns
        if (lane < NS) {
            int i = lane;
            float mx = cst[i * NS];
#pragma unroll
            for (int j = 1; j < NS; ++j) mx = fmaxf(mx, cst[i * NS + j]);
            float s = 0.f;
#pragma unroll
            for (int j = 0; j < NS; ++j) s += __expf(cst[i * NS + j] - mx);
            lzs[i] = mx + __logf(s);
        }
        __syncthreads();
        // phase 3: cost = -(x - lz) * w[gold[j]]  (BIG replaces inf)
        for (int e = lane; e < NS * NS; e += 64) {
            int i = e / NS, j = e - i * NS;
            float c = -(cst[e] - lzs[i]) * weight[g[j]];
            if (isinf(c)) c = 1e8f;
            cst[e] = c;
        }
        __syncthreads();

        // ---- shortest-augmenting-path Hungarian, f32 (whole wave) ----
        // Lane j (1..20) owns column j: p_j matched row (0=free),
        // up_j=u[p_j]; lane 0 carries phase row i / u[i].
        const float FINF = INFINITY;
        float up_j = 0.f, v_j = 0.f;
        int p_j = 0, way_j = 0;
        const bool is_col = (lane >= 1 && lane <= NS);

        for (int i = 1; i <= NS; ++i) {
            if (lane == 0) { p_j = i; up_j = 0.f; }   // p[0]=i, u[i]=0
            int j0 = 0;
            float minv_j = FINF;
            bool used_j = false;
            while (true) {
                int pp = __builtin_amdgcn_readlane(p_j, j0);   // p[j0], uniform
                if (pp == 0) break;           // free column reached
                if (lane == j0) used_j = true;
                float upp = readlane_f(up_j, j0);              // u[p[j0]]
                float cv = cst[is_col ? (pp - 1) * NS + (lane - 1) : 0];
                if (is_col && !used_j) {
                    float curv = cv - upp - v_j;
                    if (curv < minv_j) { minv_j = curv; way_j = j0; }  // strict <
                }
                float cand = (is_col && !used_j) ? minv_j : FINF;
                // 5-step min over lanes 0..31: 2 DPP + 3 swizzle
                float mval = fmin_x16(fmin_x8(fmin_x4(fmin_x2(fmin_x1(cand)))));
                // lowest-lane argmin = np.argmin tie-break
                unsigned long long bal = __ballot(cand == mval) & 0xFFFFFFFFull;
                int j1 = __ffsll(bal) - 1;
                float delta = mval;           // uniform on lanes 0..31
                if (used_j) { up_j += delta; v_j -= delta; }
                else if (is_col) minv_j -= delta;
                j0 = j1;
            }
            while (j0 != 0) {                 // augment along way[]
                int   j1   = __builtin_amdgcn_readlane(way_j, j0);
                int   pj1  = __builtin_amdgcn_readlane(p_j, j1);
                float upj1 = readlane_f(up_j, j1);
                if (lane == j0) { p_j = pj1; up_j = upj1; }
                j0 = j1;
            }
        }
        // ans[p[j]-1] = j-1
        if (is_col && p_j != 0) {
            match_col[b * NS + (p_j - 1)] = lane - 1;
        }
    } else {
        // =================== one LSE row per wave ===================
        const int row = bid - NB;
        const float4* rp = (const float4*)(outputs + (size_t)row * NC);
        // 8000 float4 = 125/lane exactly: 15 x 8-deep + 1 x 5-deep

        float m = -INFINITY;
        float s = 0.f;
        for (int it = 0; it < 15; ++it) {
            int i0 = it * 512 + lane;
            float4 a = rp[i0];
            float4 b4 = rp[i0 + 64];
            float4 c = rp[i0 + 128];
            float4 d = rp[i0 + 192];
            float4 e = rp[i0 + 256];
            float4 f = rp[i0 + 320];
            float4 g4 = rp[i0 + 384];
            float4 h = rp[i0 + 448];
            float m4 = fmaxf(fmaxf(fmaxf(max4(a), max4(b4)),
                                   fmaxf(max4(c), max4(d))),
                             fmaxf(fmaxf(max4(e), max4(f)),
                                   fmaxf(max4(g4), max4(h))));
            float nm = fmaxf(m, m4);
            float sl = __expf(a.x - nm) + __expf(a.y - nm)
                     + __expf(a.z - nm) + __expf(a.w - nm)
                     + __expf(b4.x - nm) + __expf(b4.y - nm)
                     + __expf(b4.z - nm) + __expf(b4.w - nm)
                     + __expf(c.x - nm) + __expf(c.y - nm)
                     + __expf(c.z - nm) + __expf(c.w - nm)
                     + __expf(d.x - nm) + __expf(d.y - nm)
                     + __expf(d.z - nm) + __expf(d.w - nm)
                     + __expf(e.x - nm) + __expf(e.y - nm)
                     + __expf(e.z - nm) + __expf(e.w - nm)
                     + __expf(f.x - nm) + __expf(f.y - nm)
                     + __expf(f.z - nm) + __expf(f.w - nm)
                     + __expf(g4.x - nm) + __expf(g4.y - nm)
                     + __expf(g4.z - nm) + __expf(g4.w - nm)
                     + __expf(h.x - nm) + __expf(h.y - nm)
                     + __expf(h.z - nm) + __expf(h.w - nm);
            s = s * __expf(m - nm) + sl;
            m = nm;
        }
        {   // remainder: float4 indices 7680..7999 (5 per lane)
            int i0 = 7680 + lane;
            float4 a = rp[i0];
            float4 b4 = rp[i0 + 64];
            float4 c = rp[i0 + 128];
            float4 d = rp[i0 + 192];
            float4 e = rp[i0 + 256];
            float m4 = fmaxf(fmaxf(fmaxf(max4(a), max4(b4)),
                                   fmaxf(max4(c), max4(d))), max4(e));
            float nm = fmaxf(m, m4);
            float sl = __expf(a.x - nm) + __expf(a.y - nm)
                     + __expf(a.z - nm) + __expf(a.w - nm)
                     + __expf(b4.x - nm) + __expf(b4.y - nm)
                     + __expf(b4.z - nm) + __expf(b4.w - nm)
                     + __expf(c.x - nm) + __expf(c.y - nm)
                     + __expf(c.z - nm) + __expf(c.w - nm)
                     + __expf(d.x - nm) + __expf(d.y - nm)
                     + __expf(d.z - nm) + __expf(d.w - nm)
                     + __expf(e.x - nm) + __expf(e.y - nm)
                     + __expf(e.z - nm) + __expf(e.w - nm);
            s = s * __expf(m - nm) + sl;
            m = nm;
        }
        // wave-only reduce (64 lanes), no LDS, no barrier
        for (int off = 1; off < 64; off <<= 1) {
            float om = __shfl_xor(m, off);
            float os = __shfl_xor(s, off);
            float nm = fmaxf(m, om);
            s = s * __expf(m - nm) + os * __expf(om - nm);
            m = nm;
        }
        if (lane == 0) logZ[row] = m + __logf(s);
    }
}

// ---------------------------------------------------------------------------
// Final masked-mean NLL reduce — everything L2-hot (sub_ws, logZ, match_col).
// Deterministic tree reduce, f64 accumulation. 1024 threads: 2-3 rows each.
// ---------------------------------------------------------------------------
__global__ __launch_bounds__(1024) void final_kernel(
        const int* __restrict__ match_col,
        const float* __restrict__ sub_ws,
        const float* __restrict__ logZ,
        const float* __restrict__ weight,
        const int* __restrict__ gold,
        const unsigned char* __restrict__ mask,
        float* __restrict__ out) {
    double nsum = 0.0, msum = 0.0;
    for (int r = threadIdx.x; r < NROWS; r += 1024) {
        int b = r / NS;
        int col = match_col[r];
        float x = sub_ws[(size_t)r * NS + col];          // outputs[b,i,match]
        float w = weight[gold[b * NS + col]];            // weight[match]
        float nll = -(x - logZ[r]) * w;
        float mk = mask[r] ? 1.f : 0.f;
        nsum += (double)(nll * mk);
        msum += (double)mk;
    }
    for (int off = 1; off < 64; off <<= 1) {
        nsum += __shfl_xor(nsum, off);
        msum += __shfl_xor(msum, off);
    }
    __shared__ double sn[16], sm[16];
    int wid = threadIdx.x >> 6;
    if ((threadIdx.x & 63) == 0) { sn[wid] = nsum; sm[wid] = msum; }
    __syncthreads();
    if (threadIdx.x == 0) {
        double N = 0.0, M = 0.0;
        for (int w = 0; w < 16; ++w) { N += sn[w]; M += sm[w]; }
        out[0] = (float)(N / (M + 1e-8));
    }
}

// ---------------------------------------------------------------------------
extern "C" void kernel_launch(void* const* d_in, const int* in_sizes, int n_in,
                              void* d_out, int out_size, void* d_ws, size_t ws_size,
                              hipStream_t stream) {
    const float* outputs        = (const float*)d_in[0];          // [B,S,C] f32
    const int*   gold           = (const int*)d_in[1];            // [B,S] i32
    const unsigned char* mask   = (const unsigned char*)d_in[2];  // [B,S] bool
    const float* weight         = (const float*)d_in[3];          // [C] f32
    float* out = (float*)d_out;

    // workspace layout
    char* ws = (char*)d_ws;
    int*   match_col = (int*)ws;                                   // NROWS
    float* logZ      = (float*)(ws + (size_t)NROWS * 4);           // NROWS
    float* sub_ws    = (float*)(ws + (size_t)NROWS * 8);           // NROWS*NS

    mega_kernel<<<NBLOCKS, 64, 0, stream>>>(outputs, gold, weight,
                                            match_col, sub_ws, logZ);
    final_kernel<<<1, 1024, 0, stream>>>(match_col, sub_ws, logZ, weight, gold,
                                         mask, out);
}

// Round 13
// 70.038 us; speedup vs baseline: 1.2992x; 1.2992x over previous
//
#include <hip/hip_runtime.h>
#include <hip/hip_bf16.h>
#include <math.h>

// Problem shape (fixed by setup_inputs): B=128, S=20, C=32000
#define NB 128
#define NS 20
#define NC 32000
#define NROWS (NB * NS)            // 2560
#define CPR 4                      // quarter-row chunks per row
#define NCHUNK (NROWS * CPR)       // 10240 chunks of 2000 float4
#define CHUNK_F4 2000
#define NQB (NCHUNK / 4)           // 2560 quarter-blocks (4 waves = 4 chunks each)
#define NBLOCKS (NB + NQB)         // 2688

// min with lane^1 / lane^2 via DPP quad_perm (pure VALU, no LDS)
static __device__ __forceinline__ float fmin_x1(float x) {
    int t = __builtin_amdgcn_update_dpp(0, __float_as_int(x), 0xB1, 0xf, 0xf, true); // [1,0,3,2]
    return fminf(x, __int_as_float(t));
}
static __device__ __forceinline__ float fmin_x2(float x) {
    int t = __builtin_amdgcn_update_dpp(0, __float_as_int(x), 0x4E, 0xf, 0xf, true); // [2,3,0,1]
    return fminf(x, __int_as_float(t));
}
// min with lane^4 / ^8 / ^16 via ds_swizzle bitmode (1 LDS-pipe op each)
static __device__ __forceinline__ float fmin_x4(float x) {
    int t = __builtin_amdgcn_ds_swizzle(__float_as_int(x), 0x101F);
    return fminf(x, __int_as_float(t));
}
static __device__ __forceinline__ float fmin_x8(float x) {
    int t = __builtin_amdgcn_ds_swizzle(__float_as_int(x), 0x201F);
    return fminf(x, __int_as_float(t));
}
static __device__ __forceinline__ float fmin_x16(float x) {
    int t = __builtin_amdgcn_ds_swizzle(__float_as_int(x), 0x401F);
    return fminf(x, __int_as_float(t));
}
static __device__ __forceinline__ float readlane_f(float x, int lane) {
    return __int_as_float(__builtin_amdgcn_readlane(__float_as_int(x), lane));
}
static __device__ __forceinline__ float max4(float4 a) {
    return fmaxf(fmaxf(a.x, a.y), fmaxf(a.z, a.w));
}

// ---------------------------------------------------------------------------
// Mega kernel. ZERO cross-block sync (r6/r8/r10 lessons). 256-thr blocks for
// full 8-slot/CU residency -> 32 waves/CU; every LSE wave is AUTONOMOUS and
// owns one statically-assigned quarter-row chunk (r12 lesson: BW scales with
// resident waves; r10 lesson: no atomics; r9 precedent: quarter-row partials).
//   bid <  NB : fused gather + cost + wave-parallel Hungarian (wave 0 solves,
//               all 4 waves gather), then the block retires (frees its slot).
//   bid >= NB : wave w handles chunk (bid-NB)*4+w: 2000 float4, 4-deep loads,
//               wave-only reduce, lane 0 plain-stores (m,s) partials.
// ---------------------------------------------------------------------------
__global__ __launch_bounds__(256) void mega_kernel(
        const float* __restrict__ outputs,
        const int* __restrict__ gold,
        const float* __restrict__ weight,
        int* __restrict__ match_col,     // [NROWS] assigned 0-based column per row
        float* __restrict__ sub_ws,      // [NROWS*NS] raw gathered logits
        float* __restrict__ pm,          // [NCHUNK] chunk max
        float* __restrict__ ps) {        // [NCHUNK] chunk sumexp (rel. to pm)

    const int bid = blockIdx.x;

    if (bid < NB) {
        // =================== fused cost + wave Hungarian ===================
        const int b = bid;
        const int* g = gold + b * NS;
        __shared__ float cst[NS * NS];   // sub logits, then cost, in place
        __shared__ float lzs[NS];

        // phase 1: gather outputs[b, i, gold[b, j]] + save raw logits to ws
        for (int e = threadIdx.x; e < NS * NS; e += 256) {
            int i = e / NS, j = e - i * NS;
            float x = outputs[(size_t)(b * NS + i) * NC + g[j]];
            cst[e] = x;
            sub_ws[(size_t)(b * NS + i) * NS + j] = x;
        }
        __syncthreads();
        // phase 2: per-row restricted logsumexp over the 20 gold columns
        if (threadIdx.x < NS) {
            int i = threadIdx.x;
            float mx = cst[i * NS];
#pragma unroll
            for (int j = 1; j < NS; ++j) mx = fmaxf(mx, cst[i * NS + j]);
            float s = 0.f;
#pragma unroll
            for (int j = 0; j < NS; ++j) s += __expf(cst[i * NS + j] - mx);
            lzs[i] = mx + __logf(s);
        }
        __syncthreads();
        // phase 3: cost = -(x - lz) * w[gold[j]]  (BIG replaces inf)
        for (int e = threadIdx.x; e < NS * NS; e += 256) {
            int i = e / NS, j = e - i * NS;
            float c = -(cst[e] - lzs[i]) * weight[g[j]];
            if (isinf(c)) c = 1e8f;
            cst[e] = c;
        }
        __syncthreads();
        if (threadIdx.x >= 64) return;   // waves 1..3 retire

        // ---- wave 0: shortest-augmenting-path Hungarian, f32 ----
        // Lane j (1..20) owns column j: p_j matched row (0=free),
        // up_j=u[p_j]; lane 0 carries phase row i / u[i].
        const int lane = threadIdx.x;
        const float FINF = INFINITY;
        float up_j = 0.f, v_j = 0.f;
        int p_j = 0, way_j = 0;
        const bool is_col = (lane >= 1 && lane <= NS);

        for (int i = 1; i <= NS; ++i) {
            if (lane == 0) { p_j = i; up_j = 0.f; }   // p[0]=i, u[i]=0
            int j0 = 0;
            float minv_j = FINF;
            bool used_j = false;
            while (true) {
                int pp = __builtin_amdgcn_readlane(p_j, j0);   // p[j0], uniform
                if (pp == 0) break;           // free column reached
                if (lane == j0) used_j = true;
                float upp = readlane_f(up_j, j0);              // u[p[j0]]
                float cv = cst[is_col ? (pp - 1) * NS + (lane - 1) : 0];
                if (is_col && !used_j) {
                    float curv = cv - upp - v_j;
                    if (curv < minv_j) { minv_j = curv; way_j = j0; }  // strict <
                }
                float cand = (is_col && !used_j) ? minv_j : FINF;
                // 5-step min over lanes 0..31: 2 DPP + 3 swizzle
                float mval = fmin_x16(fmin_x8(fmin_x4(fmin_x2(fmin_x1(cand)))));
                // lowest-lane argmin = np.argmin tie-break
                unsigned long long bal = __ballot(cand == mval) & 0xFFFFFFFFull;
                int j1 = __ffsll(bal) - 1;
                float delta = mval;           // uniform on lanes 0..31
                if (used_j) { up_j += delta; v_j -= delta; }
                else if (is_col) minv_j -= delta;
                j0 = j1;
            }
            while (j0 != 0) {                 // augment along way[]
                int   j1   = __builtin_amdgcn_readlane(way_j, j0);
                int   pj1  = __builtin_amdgcn_readlane(p_j, j1);
                float upj1 = readlane_f(up_j, j1);
                if (lane == j0) { p_j = pj1; up_j = upj1; }
                j0 = j1;
            }
        }
        // ans[p[j]-1] = j-1
        if (is_col && p_j != 0) {
            match_col[b * NS + (p_j - 1)] = lane - 1;
        }
    } else {
        // =================== one quarter-row chunk per wave ===================
        const int lane = threadIdx.x & 63;
        const int wid  = threadIdx.x >> 6;
        const int chunk = (bid - NB) * 4 + wid;
        const int row = chunk >> 2, q = chunk & 3;
        const float4* rp = (const float4*)outputs
                         + (size_t)row * (NC / 4) + q * CHUNK_F4;

        float m = -INFINITY;
        float s = 0.f;
        // 7 x 4-deep batches = 1792 float4
        for (int it = 0; it < 7; ++it) {
            int i0 = it * 256 + lane;
            float4 a  = rp[i0];
            float4 b4 = rp[i0 + 64];
            float4 c  = rp[i0 + 128];
            float4 d  = rp[i0 + 192];
            float m4 = fmaxf(fmaxf(max4(a), max4(b4)), fmaxf(max4(c), max4(d)));
            float nm = fmaxf(m, m4);
            float sl = __expf(a.x - nm) + __expf(a.y - nm)
                     + __expf(a.z - nm) + __expf(a.w - nm)
                     + __expf(b4.x - nm) + __expf(b4.y - nm)
                     + __expf(b4.z - nm) + __expf(b4.w - nm)
                     + __expf(c.x - nm) + __expf(c.y - nm)
                     + __expf(c.z - nm) + __expf(c.w - nm)
                     + __expf(d.x - nm) + __expf(d.y - nm)
                     + __expf(d.z - nm) + __expf(d.w - nm);
            s = s * __expf(m - nm) + sl;
            m = nm;
        }
        // remainder: 1792..1999 (208 float4; last iter partially active)
        for (int idx = 1792 + lane; idx < CHUNK_F4; idx += 64) {
            float4 x = rp[idx];
            float m4 = max4(x);
            float nm = fmaxf(m, m4);
            s = s * __expf(m - nm)
              + __expf(x.x - nm) + __expf(x.y - nm)
              + __expf(x.z - nm) + __expf(x.w - nm);
            m = nm;
        }
        // wave-only reduce (64 lanes), no LDS, no barrier
        for (int off = 1; off < 64; off <<= 1) {
            float om = __shfl_xor(m, off);
            float os = __shfl_xor(s, off);
            float nm = fmaxf(m, om);
            s = s * __expf(m - nm) + os * __expf(om - nm);
            m = nm;
        }
        if (lane == 0) { pm[chunk] = m; ps[chunk] = s; }
    }
}

// ---------------------------------------------------------------------------
// Final reduce: merge 4 chunk-partials per row in FIXED order (deterministic),
// then masked-mean NLL. Everything L2-hot. f64 tree reduce, 1024 threads.
// ---------------------------------------------------------------------------
__global__ __launch_bounds__(1024) void final_kernel(
        const int* __restrict__ match_col,
        const float* __restrict__ sub_ws,
        const float* __restrict__ pm,
        const float* __restrict__ ps,
        const float* __restrict__ weight,
        const int* __restrict__ gold,
        const unsigned char* __restrict__ mask,
        float* __restrict__ out) {
    double nsum = 0.0, msum = 0.0;
    for (int r = threadIdx.x; r < NROWS; r += 1024) {
        float M = pm[r * CPR], S = ps[r * CPR];
#pragma unroll
        for (int q = 1; q < CPR; ++q) {
            float om = pm[r * CPR + q], os = ps[r * CPR + q];
            float nm = fmaxf(M, om);
            S = S * __expf(M - nm) + os * __expf(om - nm);
            M = nm;
        }
        float lz = M + __logf(S);
        int b = r / NS;
        int col = match_col[r];
        float x = sub_ws[(size_t)r * NS + col];          // outputs[b,i,match]
        float w = weight[gold[b * NS + col]];            // weight[match]
        float nll = -(x - lz) * w;
        float mk = mask[r] ? 1.f : 0.f;
        nsum += (double)(nll * mk);
        msum += (double)mk;
    }
    for (int off = 1; off < 64; off <<= 1) {
        nsum += __shfl_xor(nsum, off);
        msum += __shfl_xor(msum, off);
    }
    __shared__ double sn[16], sm[16];
    int wid = threadIdx.x >> 6;
    if ((threadIdx.x & 63) == 0) { sn[wid] = nsum; sm[wid] = msum; }
    __syncthreads();
    if (threadIdx.x == 0) {
        double N = 0.0, M = 0.0;
        for (int w = 0; w < 16; ++w) { N += sn[w]; M += sm[w]; }
        out[0] = (float)(N / (M + 1e-8));
    }
}

// ---------------------------------------------------------------------------
extern "C" void kernel_launch(void* const* d_in, const int* in_sizes, int n_in,
                              void* d_out, int out_size, void* d_ws, size_t ws_size,
                              hipStream_t stream) {
    const float* outputs        = (const float*)d_in[0];          // [B,S,C] f32
    const int*   gold           = (const int*)d_in[1];            // [B,S] i32
    const unsigned char* mask   = (const unsigned char*)d_in[2];  // [B,S] bool
    const float* weight         = (const float*)d_in[3];          // [C] f32
    float* out = (float*)d_out;

    // workspace layout
    char* ws = (char*)d_ws;
    int*   match_col = (int*)ws;                                   // NROWS
    float* sub_ws    = (float*)(ws + (size_t)NROWS * 4);           // NROWS*NS
    float* pm        = (float*)(ws + (size_t)NROWS * 4
                                + (size_t)NROWS * NS * 4);         // NCHUNK
    float* ps        = pm + NCHUNK;                                // NCHUNK

    mega_kernel<<<NBLOCKS, 256, 0, stream>>>(outputs, gold, weight,
                                             match_col, sub_ws, pm, ps);
    final_kernel<<<1, 1024, 0, stream>>>(match_col, sub_ws, pm, ps, weight,
                                         gold, mask, out);
}